// Round 6
// baseline (257.661 us; speedup 1.0000x reference)
//
#include <hip/hip_runtime.h>
#include <hip/hip_bf16.h>
#include <math.h>

#define BATCH 8
#define SQ 2048
#define SK 2048
#define DD 512
#define DV 512
#define RP 40   // LDS row pitch in shorts (80 B); frag b128 reads ~2-way (structural floor)

typedef short bf16x8_t __attribute__((ext_vector_type(8)));
typedef float f32x4_t __attribute__((ext_vector_type(4)));

// packed RTNE fp32x2 -> bf16x2
__device__ __forceinline__ unsigned int pk_bf16(float a, float b) {
    __hip_bfloat162 h = __float22bfloat162_rn(float2{a, b});
    unsigned int u;
    __builtin_memcpy(&u, &h, 4);
    return u;
}
__device__ __forceinline__ float from_hi(unsigned int u) {
    return __builtin_bit_cast(float, u);
}

// ---------------------------------------------------------------------------
// Kernel 1: M[b] += K[b]^T V[b] partials (un-scaled), t-split by 8, via
// fp32 atomicAdd into M ([8][512][512] fp32 = 8 MB in d_ws, zeroed first).
// 128(d) x 128(v) tile per block over a 256-long t-range, BK=32.
// Grid 4x4x64 = 1024 blocks = 4 blocks/CU (was 2 -- the occupancy fix).
// 3-term split MFMA: Kh*Vh + Kh*Vl + Kl*Vh.
// ---------------------------------------------------------------------------
__global__ __launch_bounds__(256) void ktv_mfma(const float* __restrict__ Kp,
                                                const float* __restrict__ Vp,
                                                float* __restrict__ Mg) {
    const int b  = blockIdx.z & 7;
    const int ts = blockIdx.z >> 3;   // 0..7
    const int d0 = blockIdx.x * 128;
    const int v0 = blockIdx.y * 128;
    const float* Kb = Kp + (size_t)b * SK * DD;
    const float* Vb = Vp + (size_t)b * SK * DV;

    __shared__ __align__(16) unsigned short Kh[128 * RP], Kl[128 * RP],
                                            Vh[128 * RP], Vl[128 * RP];

    const int tid  = threadIdx.x;
    const int lane = tid & 63;
    const int w    = tid >> 6;
    const int wd   = (w & 1) * 64;
    const int wv   = (w >> 1) * 64;
    const int uu   = tid >> 5;   // 0..7  (t-pair selector)
    const int xx   = tid & 31;   // d/v column selector

    f32x4_t acc[4][4];
#pragma unroll
    for (int i = 0; i < 4; ++i)
#pragma unroll
        for (int j = 0; j < 4; ++j) acc[i][j] = (f32x4_t){0.f, 0.f, 0.f, 0.f};

    const int tb = ts * 256;
    for (int t0 = 0; t0 < 256; t0 += 32) {
        // ---- stage K,V (32 t x 128 cols), transposed into LDS, bf16 hi/lo ----
#pragma unroll
        for (int p = 0; p < 2; ++p) {
            const int t  = 16 * p + 2 * uu;                 // even local t
            const int to = (t >> 3) * 8 + (t & 7);          // within-row offset
            const size_t gr = (size_t)(tb + t0 + t);
#pragma unroll
            for (int c = 0; c < 4; ++c) {
                const int d   = xx + 32 * c;
                const int off = d * RP + to;
                {
                    const float f0 = Kb[gr * DD + d0 + d];
                    const float f1 = Kb[(gr + 1) * DD + d0 + d];
                    const unsigned int h = pk_bf16(f0, f1);
                    const float r0 = f0 - from_hi(h << 16);
                    const float r1 = f1 - from_hi(h & 0xFFFF0000u);
                    *(unsigned int*)(Kh + off) = h;
                    *(unsigned int*)(Kl + off) = pk_bf16(r0, r1);
                }
                {
                    const float f0 = Vb[gr * DV + v0 + d];
                    const float f1 = Vb[(gr + 1) * DV + v0 + d];
                    const unsigned int h = pk_bf16(f0, f1);
                    const float r0 = f0 - from_hi(h << 16);
                    const float r1 = f1 - from_hi(h & 0xFFFF0000u);
                    *(unsigned int*)(Vh + off) = h;
                    *(unsigned int*)(Vl + off) = pk_bf16(r0, r1);
                }
            }
        }
        __syncthreads();

        // ---- MFMA ----
        const int kq = lane >> 4;
        const int mr = lane & 15;
        bf16x8_t ah[4], al_[4];
#pragma unroll
        for (int tm = 0; tm < 4; ++tm) {
            const int off = (wd + tm * 16 + mr) * RP + kq * 8;
            ah[tm]  = *(const bf16x8_t*)(Kh + off);
            al_[tm] = *(const bf16x8_t*)(Kl + off);
        }
#pragma unroll
        for (int tn = 0; tn < 4; ++tn) {
            const int off = (wv + tn * 16 + mr) * RP + kq * 8;
            const bf16x8_t bh = *(const bf16x8_t*)(Vh + off);
            const bf16x8_t bl = *(const bf16x8_t*)(Vl + off);
#pragma unroll
            for (int tm = 0; tm < 4; ++tm) {
                acc[tm][tn] = __builtin_amdgcn_mfma_f32_16x16x32_bf16(ah[tm], bh, acc[tm][tn], 0, 0, 0);
                acc[tm][tn] = __builtin_amdgcn_mfma_f32_16x16x32_bf16(ah[tm], bl, acc[tm][tn], 0, 0, 0);
                acc[tm][tn] = __builtin_amdgcn_mfma_f32_16x16x32_bf16(al_[tm], bh, acc[tm][tn], 0, 0, 0);
            }
        }
        __syncthreads();
    }

    // epilogue: atomic fp32 accumulate into M (8 ts-blocks per address total)
    float* Mb = Mg + (size_t)b * DD * DV;
    const int quad = lane >> 4;
    const int col  = lane & 15;
#pragma unroll
    for (int tm = 0; tm < 4; ++tm)
#pragma unroll
        for (int tn = 0; tn < 4; ++tn)
#pragma unroll
            for (int r = 0; r < 4; ++r) {
                const int d = d0 + wd + tm * 16 + quad * 4 + r;
                const int v = v0 + wv + tn * 16 + col;
                atomicAdd(&Mb[(size_t)d * DV + v], acc[tm][tn][r]);
            }
}

// ---------------------------------------------------------------------------
// Kernel 2: X[b] = Q[b] @ (M[b]*scale) via 3-term split MFMA, M read as fp32
// and converted/split on the fly. Tile 128(q) x 64(v), BK=32.
// Grid 16x8x8 = 1024 blocks = 4 blocks/CU.
// ---------------------------------------------------------------------------
__global__ __launch_bounds__(256) void qm_mfma(const float* __restrict__ Qp,
                                               const float* __restrict__ Mg,
                                               float* __restrict__ Xp) {
    const int b  = blockIdx.z;
    const int q0 = blockIdx.x * 128;
    const int v0 = blockIdx.y * 64;
    const float* Qb = Qp + (size_t)b * SQ * DD;
    const float* Mb = Mg + (size_t)b * DD * DV;

    __shared__ __align__(16) unsigned short Qh[128 * RP], Ql[128 * RP],
                                            Bh[64 * RP], Bl[64 * RP];

    const int tid  = threadIdx.x;
    const int lane = tid & 63;
    const int w    = tid >> 6;
    const int wq   = (w & 1) * 64;
    const int wv   = (w >> 1) * 32;

    f32x4_t acc[4][2];
#pragma unroll
    for (int i = 0; i < 4; ++i)
#pragma unroll
        for (int j = 0; j < 2; ++j) acc[i][j] = (f32x4_t){0.f, 0.f, 0.f, 0.f};

    const float s = 0.04419417382415922f;  // 1/sqrt(512)

    for (int k0 = 0; k0 < DD; k0 += 32) {
        // ---- stage Q (float4 load, packed split), natural [q][k] layout ----
#pragma unroll
        for (int p = 0; p < 4; ++p) {
            const int q  = p * 32 + (tid >> 3);
            const int dc = (tid & 7) * 4;
            const float4 f = *(const float4*)&Qb[(size_t)(q0 + q) * DD + k0 + dc];
            const unsigned int h01 = pk_bf16(f.x, f.y);
            const unsigned int h23 = pk_bf16(f.z, f.w);
            const float r0 = f.x - from_hi(h01 << 16);
            const float r1 = f.y - from_hi(h01 & 0xFFFF0000u);
            const float r2 = f.z - from_hi(h23 << 16);
            const float r3 = f.w - from_hi(h23 & 0xFFFF0000u);
            const int off = q * RP + dc;
            *(uint2*)(Qh + off) = make_uint2(h01, h23);
            *(uint2*)(Ql + off) = make_uint2(pk_bf16(r0, r1), pk_bf16(r2, r3));
        }
        // ---- stage B from fp32 M: 32 k x 64 v, transposed, scaled, split ----
        {
            const int kp = tid >> 4;       // 0..15 -> k = 2*kp
            const int k  = 2 * kp;
            const int vx = tid & 15;
#pragma unroll
            for (int c = 0; c < 4; ++c) {
                const int v = vx + 16 * c;
                const float f0 = Mb[(size_t)(k0 + k) * DV + v0 + v] * s;
                const float f1 = Mb[(size_t)(k0 + k + 1) * DV + v0 + v] * s;
                const unsigned int h = pk_bf16(f0, f1);
                const float r0 = f0 - from_hi(h << 16);
                const float r1 = f1 - from_hi(h & 0xFFFF0000u);
                const int off = v * RP + k;
                *(unsigned int*)(Bh + off) = h;
                *(unsigned int*)(Bl + off) = pk_bf16(r0, r1);
            }
        }
        __syncthreads();

        const int kq = lane >> 4;
        const int mr = lane & 15;
        bf16x8_t ah[4], al_[4];
#pragma unroll
        for (int tm = 0; tm < 4; ++tm) {
            const int off = (wq + tm * 16 + mr) * RP + kq * 8;
            ah[tm]  = *(const bf16x8_t*)(Qh + off);
            al_[tm] = *(const bf16x8_t*)(Ql + off);
        }
#pragma unroll
        for (int tn = 0; tn < 2; ++tn) {
            const int off = (wv + tn * 16 + mr) * RP + kq * 8;
            const bf16x8_t bh = *(const bf16x8_t*)(Bh + off);
            const bf16x8_t bl = *(const bf16x8_t*)(Bl + off);
#pragma unroll
            for (int tm = 0; tm < 4; ++tm) {
                acc[tm][tn] = __builtin_amdgcn_mfma_f32_16x16x32_bf16(ah[tm], bh, acc[tm][tn], 0, 0, 0);
                acc[tm][tn] = __builtin_amdgcn_mfma_f32_16x16x32_bf16(ah[tm], bl, acc[tm][tn], 0, 0, 0);
                acc[tm][tn] = __builtin_amdgcn_mfma_f32_16x16x32_bf16(al_[tm], bh, acc[tm][tn], 0, 0, 0);
            }
        }
        __syncthreads();
    }

    float* Xb = Xp + (size_t)b * SQ * DV;
    const int quad = lane >> 4;
    const int col  = lane & 15;
#pragma unroll
    for (int tm = 0; tm < 4; ++tm)
#pragma unroll
        for (int tn = 0; tn < 2; ++tn)
#pragma unroll
            for (int r = 0; r < 4; ++r)
                Xb[(size_t)(q0 + wq + tm * 16 + quad * 4 + r) * DV + v0 + wv + tn * 16 + col] = acc[tm][tn][r];
}

// ---------------------------------------------------------------------------
// Kernel 3: in-place masked softmax over last dim (512). One wave per row.
// ---------------------------------------------------------------------------
__global__ __launch_bounds__(256) void softmax_kernel(float* __restrict__ X,
                                                      const int* __restrict__ vlen) {
    const int wave = threadIdx.x >> 6;
    const int lane = threadIdx.x & 63;
    const int row  = blockIdx.x * 4 + wave;
    const int q    = row & (SQ - 1);
    float* xr = X + (size_t)row * DV;
    const int vl = vlen[q];

    float v[8];
#pragma unroll
    for (int u = 0; u < 2; ++u) {
        const int j0 = u * 256 + lane * 4;
        const float4 f = *(const float4*)&xr[j0];
        v[u * 4 + 0] = (j0 + 0 > vl) ? -1.0e6f : f.x;
        v[u * 4 + 1] = (j0 + 1 > vl) ? -1.0e6f : f.y;
        v[u * 4 + 2] = (j0 + 2 > vl) ? -1.0e6f : f.z;
        v[u * 4 + 3] = (j0 + 3 > vl) ? -1.0e6f : f.w;
    }

    float m = v[0];
#pragma unroll
    for (int i = 1; i < 8; ++i) m = fmaxf(m, v[i]);
#pragma unroll
    for (int off = 32; off > 0; off >>= 1) m = fmaxf(m, __shfl_xor(m, off, 64));

    float ssum = 0.f;
#pragma unroll
    for (int i = 0; i < 8; ++i) {
        v[i] = __expf(v[i] - m);
        ssum += v[i];
    }
#pragma unroll
    for (int off = 32; off > 0; off >>= 1) ssum += __shfl_xor(ssum, off, 64);

    const float inv = 1.0f / ssum;
#pragma unroll
    for (int u = 0; u < 2; ++u) {
        const int j0 = u * 256 + lane * 4;
        float4 o;
        o.x = v[u * 4 + 0] * inv;
        o.y = v[u * 4 + 1] * inv;
        o.z = v[u * 4 + 2] * inv;
        o.w = v[u * 4 + 3] * inv;
        *(float4*)&xr[j0] = o;
    }
}

extern "C" void kernel_launch(void* const* d_in, const int* in_sizes, int n_in,
                              void* d_out, int out_size, void* d_ws, size_t ws_size,
                              hipStream_t stream) {
    const float* Kp   = (const float*)d_in[0];
    const float* Vp   = (const float*)d_in[1];
    const float* Qp   = (const float*)d_in[2];
    const int*   vlen = (const int*)d_in[3];
    float* out = (float*)d_out;
    float* M   = (float*)d_ws;   // [8][512][512] fp32 = exactly 8 MB (proven-safe)

    hipMemsetAsync(d_ws, 0, (size_t)BATCH * DD * DV * sizeof(float), stream);
    ktv_mfma<<<dim3(4, 4, 64), 256, 0, stream>>>(Kp, Vp, M);
    qm_mfma<<<dim3(16, 8, 8), 256, 0, stream>>>(Qp, M, out);
    softmax_kernel<<<dim3(BATCH * SQ / 4), 256, 0, stream>>>(out, vlen);
}

// Round 7
// 195.432 us; speedup vs baseline: 1.3184x; 1.3184x over previous
//
#include <hip/hip_runtime.h>
#include <hip/hip_bf16.h>
#include <math.h>

#define BATCH 8
#define SQ 2048
#define SK 2048
#define DD 512
#define DV 512
#define RP 40   // LDS row pitch in shorts (80 B). Frag b128 reads are 2-way (free, m136);
                // the 2^23 SQ_LDS_BANK_CONFLICT floor is structural -- do not chase.

typedef short bf16x8_t __attribute__((ext_vector_type(8)));
typedef float f32x4_t __attribute__((ext_vector_type(4)));

// packed RTNE fp32x2 -> bf16x2 (v_cvt_pk_bf16_f32)
__device__ __forceinline__ unsigned int pk_bf16(float a, float b) {
    __hip_bfloat162 h = __float22bfloat162_rn(float2{a, b});
    unsigned int u;
    __builtin_memcpy(&u, &h, 4);
    return u;
}
__device__ __forceinline__ float from_hi(unsigned int u) {
    return __builtin_bit_cast(float, u);
}

// ---------------------------------------------------------------------------
// Kernel 1: fp32 partials of K^T V (un-scaled), t-split by 4.
// Mpart: [ts(4)][b(8)][d(512)][v(512)] fp32 == 32 MB, lives in d_out.
// 128x128 tile, BK=32, register-prefetch pipeline: next tile's global loads
// issue right after the first barrier and fly under the 48-MFMA block
// (issuing before a barrier is useless -- compiler drains vmcnt(0) there).
// 3-term split MFMA: Kh*Vh + Kh*Vl + Kl*Vh.
// ---------------------------------------------------------------------------
__global__ __launch_bounds__(256) void ktv_mfma(const float* __restrict__ Kp,
                                                const float* __restrict__ Vp,
                                                float* __restrict__ Mpart) {
    const int b  = blockIdx.z & 7;
    const int ts = blockIdx.z >> 3;
    const int d0 = blockIdx.x * 128;
    const int v0 = blockIdx.y * 128;
    const float* Kb = Kp + (size_t)b * SK * DD;
    const float* Vb = Vp + (size_t)b * SK * DV;

    __shared__ __align__(16) unsigned short Kh[128 * RP], Kl[128 * RP],
                                            Vh[128 * RP], Vl[128 * RP];

    const int tid  = threadIdx.x;
    const int lane = tid & 63;
    const int w    = tid >> 6;
    const int wd   = (w & 1) * 64;
    const int wv   = (w >> 1) * 64;
    const int uu   = tid >> 5;   // 0..7  (t-pair selector)
    const int xx   = tid & 31;   // d/v column selector

    f32x4_t acc[4][4];
#pragma unroll
    for (int i = 0; i < 4; ++i)
#pragma unroll
        for (int j = 0; j < 4; ++j) acc[i][j] = (f32x4_t){0.f, 0.f, 0.f, 0.f};

    const int tb = ts * 512;

    // prefetch registers: K and V, (p,c) x {t, t+1}
    float kr0[2][4], kr1[2][4], vr0[2][4], vr1[2][4];
    auto load_tile = [&](int t0l) {
#pragma unroll
        for (int p = 0; p < 2; ++p) {
            const int t = 16 * p + 2 * uu;
            const size_t gr = (size_t)(tb + t0l + t);
#pragma unroll
            for (int c = 0; c < 4; ++c) {
                const int d = xx + 32 * c;
                kr0[p][c] = Kb[gr * DD + d0 + d];
                kr1[p][c] = Kb[(gr + 1) * DD + d0 + d];
                vr0[p][c] = Vb[gr * DV + v0 + d];
                vr1[p][c] = Vb[(gr + 1) * DV + v0 + d];
            }
        }
    };

    load_tile(0);
    for (int t0 = 0; t0 < 512; t0 += 32) {
        // ---- cvt + LDS store from prefetched regs ----
#pragma unroll
        for (int p = 0; p < 2; ++p) {
            const int t  = 16 * p + 2 * uu;
            const int to = (t >> 3) * 8 + (t & 7);
#pragma unroll
            for (int c = 0; c < 4; ++c) {
                const int d   = xx + 32 * c;
                const int off = d * RP + to;
                {
                    const unsigned int h = pk_bf16(kr0[p][c], kr1[p][c]);
                    const float r0 = kr0[p][c] - from_hi(h << 16);
                    const float r1 = kr1[p][c] - from_hi(h & 0xFFFF0000u);
                    *(unsigned int*)(Kh + off) = h;
                    *(unsigned int*)(Kl + off) = pk_bf16(r0, r1);
                }
                {
                    const unsigned int h = pk_bf16(vr0[p][c], vr1[p][c]);
                    const float r0 = vr0[p][c] - from_hi(h << 16);
                    const float r1 = vr1[p][c] - from_hi(h & 0xFFFF0000u);
                    *(unsigned int*)(Vh + off) = h;
                    *(unsigned int*)(Vl + off) = pk_bf16(r0, r1);
                }
            }
        }
        __syncthreads();

        // issue next tile's loads now -- they overlap the MFMA block below
        if (t0 + 32 < 512) load_tile(t0 + 32);

        // ---- MFMA ----
        const int kq = lane >> 4;
        const int mr = lane & 15;
        bf16x8_t ah[4], al_[4];
#pragma unroll
        for (int tm = 0; tm < 4; ++tm) {
            const int off = (wd + tm * 16 + mr) * RP + kq * 8;
            ah[tm]  = *(const bf16x8_t*)(Kh + off);
            al_[tm] = *(const bf16x8_t*)(Kl + off);
        }
#pragma unroll
        for (int tn = 0; tn < 4; ++tn) {
            const int off = (wv + tn * 16 + mr) * RP + kq * 8;
            const bf16x8_t bh = *(const bf16x8_t*)(Vh + off);
            const bf16x8_t bl = *(const bf16x8_t*)(Vl + off);
#pragma unroll
            for (int tm = 0; tm < 4; ++tm) {
                acc[tm][tn] = __builtin_amdgcn_mfma_f32_16x16x32_bf16(ah[tm], bh, acc[tm][tn], 0, 0, 0);
                acc[tm][tn] = __builtin_amdgcn_mfma_f32_16x16x32_bf16(ah[tm], bl, acc[tm][tn], 0, 0, 0);
                acc[tm][tn] = __builtin_amdgcn_mfma_f32_16x16x32_bf16(al_[tm], bh, acc[tm][tn], 0, 0, 0);
            }
        }
        __syncthreads();
    }

    // epilogue: fp32 partial (C/D layout: col=lane&15, row=quad*4+reg)
    float* Mp = Mpart + (size_t)(ts * 8 + b) * DD * DV;
    const int quad = lane >> 4;
    const int col  = lane & 15;
#pragma unroll
    for (int tm = 0; tm < 4; ++tm)
#pragma unroll
        for (int tn = 0; tn < 4; ++tn)
#pragma unroll
            for (int r = 0; r < 4; ++r) {
                const int d = d0 + wd + tm * 16 + quad * 4 + r;
                const int v = v0 + wv + tn * 16 + col;
                Mp[(size_t)d * DV + v] = acc[tm][tn][r];
            }
}

// ---------------------------------------------------------------------------
// Kernel 2: sum 4 partials, scale by 1/sqrt(512), transpose [d][v]->[v][d],
// emit Mt_hi/Mt_lo bf16 [b][v][d] into d_ws (8 MB total).
// ---------------------------------------------------------------------------
__global__ __launch_bounds__(256) void reduce_cvt(const float* __restrict__ Mpart,
                                                  unsigned short* __restrict__ Mth,
                                                  unsigned short* __restrict__ Mtl) {
    const int b  = blockIdx.z;
    const int d0 = blockIdx.x * 64;
    const int v0 = blockIdx.y * 64;
    __shared__ float T[64][65];
    const int i  = threadIdx.x;
    const int xr = i >> 4;   // 0..15
    const int xc = i & 15;   // 0..15

#pragma unroll
    for (int e = 0; e < 4; ++e) {
        const int dr = e * 16 + xr;
        float sx = 0.f, sy = 0.f, sz = 0.f, sw = 0.f;
#pragma unroll
        for (int sl = 0; sl < 4; ++sl) {
            const float4 f = *(const float4*)&Mpart[((size_t)(sl * 8 + b) * DD + d0 + dr) * DV + v0 + xc * 4];
            sx += f.x; sy += f.y; sz += f.z; sw += f.w;
        }
        T[dr][xc * 4 + 0] = sx;
        T[dr][xc * 4 + 1] = sy;
        T[dr][xc * 4 + 2] = sz;
        T[dr][xc * 4 + 3] = sw;
    }
    __syncthreads();

    const float s = 0.04419417382415922f;  // 1/sqrt(512)
#pragma unroll
    for (int e = 0; e < 4; ++e) {
        const int v = e * 16 + xr;
        float m[4], r[4];
        unsigned int hv[2], lv[2];
#pragma unroll
        for (int j = 0; j < 4; ++j) m[j] = T[xc * 4 + j][v] * s;
#pragma unroll
        for (int j = 0; j < 2; ++j) {
            hv[j] = pk_bf16(m[2 * j], m[2 * j + 1]);
            r[2 * j]     = m[2 * j]     - from_hi(hv[j] << 16);
            r[2 * j + 1] = m[2 * j + 1] - from_hi(hv[j] & 0xFFFF0000u);
            lv[j] = pk_bf16(r[2 * j], r[2 * j + 1]);
        }
        const size_t o = ((size_t)b * DV + v0 + v) * DD + d0 + xc * 4;
        *(uint2*)&Mth[o] = make_uint2(hv[0], hv[1]);
        *(uint2*)&Mtl[o] = make_uint2(lv[0], lv[1]);
    }
}

// ---------------------------------------------------------------------------
// Kernel 3: X[b] = Q[b] @ M[b] via 3-term split MFMA. B pre-split bf16
// k-contiguous from ws; Q converted on the fly. 128x128 tiles, BK=32,
// same register-prefetch pipeline as ktv.
// ---------------------------------------------------------------------------
__global__ __launch_bounds__(256) void qm_mfma(const float* __restrict__ Qp,
                                               const unsigned short* __restrict__ Mth,
                                               const unsigned short* __restrict__ Mtl,
                                               float* __restrict__ Xp) {
    const int b  = blockIdx.z;
    const int q0 = blockIdx.x * 128;
    const int v0 = blockIdx.y * 128;
    const float* Qb = Qp + (size_t)b * SQ * DD;
    const unsigned short* Bhg = Mth + (size_t)b * DV * DD;
    const unsigned short* Blg = Mtl + (size_t)b * DV * DD;

    __shared__ __align__(16) unsigned short Qh[128 * RP], Ql[128 * RP],
                                            Bh[128 * RP], Bl[128 * RP];

    const int tid  = threadIdx.x;
    const int lane = tid & 63;
    const int w    = tid >> 6;
    const int wq   = (w & 1) * 64;
    const int wv   = (w >> 1) * 64;

    f32x4_t acc[4][4];
#pragma unroll
    for (int i = 0; i < 4; ++i)
#pragma unroll
        for (int j = 0; j < 4; ++j) acc[i][j] = (f32x4_t){0.f, 0.f, 0.f, 0.f};

    // prefetch registers
    float4 pq[4];
    bf16x8_t pbh[2], pbl[2];
    const int qrow = tid >> 3;          // 0..31
    const int qdc  = (tid & 7) * 4;     // 0..28
    const int brow = tid >> 2;          // 0..63
    const int bkq  = tid & 3;           // 0..3
    auto load_tile = [&](int k0l) {
#pragma unroll
        for (int p = 0; p < 4; ++p)
            pq[p] = *(const float4*)&Qb[(size_t)(q0 + p * 32 + qrow) * DD + k0l + qdc];
#pragma unroll
        for (int p = 0; p < 2; ++p) {
            const size_t go = (size_t)(v0 + p * 64 + brow) * DD + k0l + bkq * 8;
            pbh[p] = *(const bf16x8_t*)&Bhg[go];
            pbl[p] = *(const bf16x8_t*)&Blg[go];
        }
    };

    load_tile(0);
    for (int k0 = 0; k0 < DD; k0 += 32) {
        // ---- stage Q (cvt+split) and B (straight copy) from regs ----
#pragma unroll
        for (int p = 0; p < 4; ++p) {
            const float4 f = pq[p];
            const unsigned int h01 = pk_bf16(f.x, f.y);
            const unsigned int h23 = pk_bf16(f.z, f.w);
            const float r0 = f.x - from_hi(h01 << 16);
            const float r1 = f.y - from_hi(h01 & 0xFFFF0000u);
            const float r2 = f.z - from_hi(h23 << 16);
            const float r3 = f.w - from_hi(h23 & 0xFFFF0000u);
            const int off = (p * 32 + qrow) * RP + qdc;
            *(uint2*)(Qh + off) = make_uint2(h01, h23);
            *(uint2*)(Ql + off) = make_uint2(pk_bf16(r0, r1), pk_bf16(r2, r3));
        }
#pragma unroll
        for (int p = 0; p < 2; ++p) {
            const int off = (p * 64 + brow) * RP + bkq * 8;
            *(bf16x8_t*)(Bh + off) = pbh[p];
            *(bf16x8_t*)(Bl + off) = pbl[p];
        }
        __syncthreads();

        if (k0 + 32 < DD) load_tile(k0 + 32);

        const int kq = lane >> 4;
        const int mr = lane & 15;
        bf16x8_t ah[4], al_[4];
#pragma unroll
        for (int tm = 0; tm < 4; ++tm) {
            const int off = (wq + tm * 16 + mr) * RP + kq * 8;
            ah[tm]  = *(const bf16x8_t*)(Qh + off);
            al_[tm] = *(const bf16x8_t*)(Ql + off);
        }
#pragma unroll
        for (int tn = 0; tn < 4; ++tn) {
            const int off = (wv + tn * 16 + mr) * RP + kq * 8;
            const bf16x8_t bh = *(const bf16x8_t*)(Bh + off);
            const bf16x8_t bl = *(const bf16x8_t*)(Bl + off);
#pragma unroll
            for (int tm = 0; tm < 4; ++tm) {
                acc[tm][tn] = __builtin_amdgcn_mfma_f32_16x16x32_bf16(ah[tm], bh, acc[tm][tn], 0, 0, 0);
                acc[tm][tn] = __builtin_amdgcn_mfma_f32_16x16x32_bf16(ah[tm], bl, acc[tm][tn], 0, 0, 0);
                acc[tm][tn] = __builtin_amdgcn_mfma_f32_16x16x32_bf16(al_[tm], bh, acc[tm][tn], 0, 0, 0);
            }
        }
        __syncthreads();
    }

    float* Xb = Xp + (size_t)b * SQ * DV;
    const int quad = lane >> 4;
    const int col  = lane & 15;
#pragma unroll
    for (int tm = 0; tm < 4; ++tm)
#pragma unroll
        for (int tn = 0; tn < 4; ++tn)
#pragma unroll
            for (int r = 0; r < 4; ++r)
                Xb[(size_t)(q0 + wq + tm * 16 + quad * 4 + r) * DV + v0 + wv + tn * 16 + col] = acc[tm][tn][r];
}

// ---------------------------------------------------------------------------
// Kernel 4: in-place masked softmax over last dim (512). One wave per row.
// ---------------------------------------------------------------------------
__global__ __launch_bounds__(256) void softmax_kernel(float* __restrict__ X,
                                                      const int* __restrict__ vlen) {
    const int wave = threadIdx.x >> 6;
    const int lane = threadIdx.x & 63;
    const int row  = blockIdx.x * 4 + wave;
    const int q    = row & (SQ - 1);
    float* xr = X + (size_t)row * DV;
    const int vl = vlen[q];

    float v[8];
#pragma unroll
    for (int u = 0; u < 2; ++u) {
        const int j0 = u * 256 + lane * 4;
        const float4 f = *(const float4*)&xr[j0];
        v[u * 4 + 0] = (j0 + 0 > vl) ? -1.0e6f : f.x;
        v[u * 4 + 1] = (j0 + 1 > vl) ? -1.0e6f : f.y;
        v[u * 4 + 2] = (j0 + 2 > vl) ? -1.0e6f : f.z;
        v[u * 4 + 3] = (j0 + 3 > vl) ? -1.0e6f : f.w;
    }

    float m = v[0];
#pragma unroll
    for (int i = 1; i < 8; ++i) m = fmaxf(m, v[i]);
#pragma unroll
    for (int off = 32; off > 0; off >>= 1) m = fmaxf(m, __shfl_xor(m, off, 64));

    float ssum = 0.f;
#pragma unroll
    for (int i = 0; i < 8; ++i) {
        v[i] = __expf(v[i] - m);
        ssum += v[i];
    }
#pragma unroll
    for (int off = 32; off > 0; off >>= 1) ssum += __shfl_xor(ssum, off, 64);

    const float inv = 1.0f / ssum;
#pragma unroll
    for (int u = 0; u < 2; ++u) {
        const int j0 = u * 256 + lane * 4;
        float4 o;
        o.x = v[u * 4 + 0] * inv;
        o.y = v[u * 4 + 1] * inv;
        o.z = v[u * 4 + 2] * inv;
        o.w = v[u * 4 + 3] * inv;
        *(float4*)&xr[j0] = o;
    }
}

extern "C" void kernel_launch(void* const* d_in, const int* in_sizes, int n_in,
                              void* d_out, int out_size, void* d_ws, size_t ws_size,
                              hipStream_t stream) {
    const float* Kp   = (const float*)d_in[0];
    const float* Vp   = (const float*)d_in[1];
    const float* Qp   = (const float*)d_in[2];
    const int*   vlen = (const int*)d_in[3];
    float* out = (float*)d_out;

    // ws: Mt_hi (4 MB) | Mt_lo (4 MB) -- proven-safe 8 MB footprint.
    unsigned short* Mth = (unsigned short*)d_ws;
    unsigned short* Mtl = Mth + (size_t)BATCH * DD * DV;
    // fp32 partials (4 x 8 MB = 32 MB) live in d_out; overwritten by qm later.
    float* Mpart = out;

    ktv_mfma<<<dim3(4, 4, 32), 256, 0, stream>>>(Kp, Vp, Mpart);
    reduce_cvt<<<dim3(8, 8, 8), 256, 0, stream>>>(Mpart, Mth, Mtl);
    qm_mfma<<<dim3(16, 4, 8), 256, 0, stream>>>(Qp, Mth, Mtl, out);
    softmax_kernel<<<dim3(BATCH * SQ / 4), 256, 0, stream>>>(out, vlen);
}